// Round 23
// baseline (50.652 us; speedup 1.0000x reference)
//
#include <hip/hip_runtime.h>
#include <hip/hip_bf16.h>

#define NPOS 2744      // 14^3
#define BB 4
#define BNTOT (BB*NPOS)   // 10976
#define RELVOL 19683   // 27^3
#define EROWS2 19688       // padded elems per k-row (mult of 4)
#define NRT 196            // (zm,ym) m-row-tiles
#define NV2 (NRT*2*64)     // vfrag entries
#define N4T 1024           // lc
#define NGRP3 29           // 96-n groups
#define WDW3 5220          // dwords per LDS window copy (10440 elems)

typedef __bf16 bf16x8 __attribute__((ext_vector_type(8)));
typedef float f32x16 __attribute__((ext_vector_type(16)));

// ---- workspace layout (bytes) ----
#define WS_Q  0u           // f32 [4][64][2744]
#define WS_K  2809856u     // f32 [4][16][2744]  (dead after k_sl; vfrag aliases it)
#define WS_V  3512320u     // f32 [4][16][2744]
#define WS_ST 4214784u     // f32 [160] scale/shift
#define WS_LA 4216192u     // f32 [1088] lc accum
#define WS_LC 4220544u     // f32 [4][16][16]
#define WS_E2 4224640u     // u16 [16][EROWS2] bf16 E table, k-MAJOR (630KB) + 2KB pad
#define WS_LP 4856704u     // u16 [4 b][2744 n][16 k][16 v] bf16 lambda_p (5.6MB)
#define WS_VF WS_K         // uint4 [196][2][64] v B-fragments

__device__ inline unsigned short f2bf(float f) {
  unsigned int u = __float_as_uint(f);
  return (unsigned short)((u + 0x7fffu + ((u >> 16) & 1u)) >> 16);
}
__device__ inline unsigned int fsh(unsigned int hi, unsigned int lo, int shbits) {
  return (unsigned int)(((((unsigned long long)hi) << 32) | lo) >> shbits);
}
__device__ inline unsigned int pk2(float a, float b) {
  return (unsigned int)f2bf(a) | ((unsigned int)f2bf(b) << 16);
}
__device__ inline float ubf(unsigned int d, int hf) {
  return __uint_as_float(((d >> hf) & 0xFFFFu) << 16);
}

// ---------------- P1: qkv projections (blocks 0..1031, 4-ch groups) + E-table build (1032..1339) ----------------
__global__ __launch_bounds__(256) void k_qkv(const float* __restrict__ x,
    const float* __restrict__ Wq, const float* __restrict__ Wk, const float* __restrict__ Wv,
    const float* __restrict__ rpe,
    float* __restrict__ qws, float* __restrict__ kws, float* __restrict__ vws,
    unsigned short* __restrict__ ebf, float* __restrict__ la) {
  int bid = blockIdx.x;
  int tid = threadIdx.x;
  if (bid >= 1032) {
    int bid2 = bid - 1032;                     // 0..307
    if (bid2 == 0 && tid < 272) ((float4*)la)[tid] = make_float4(0.f, 0.f, 0.f, 0.f);
    const int TOT = 16 * EROWS2 + 1024;        // +1024 elems: zero pad after table
    for (int e = bid2 * 256 + tid; e < TOT; e += 308 * 256) {
      if (e < 16 * EROWS2) {
        int k = e / EROWS2;
        int i = e - k * EROWS2;
        float val = (i < RELVOL) ? rpe[i * 16 + k] : 0.f;
        ebf[e] = f2bf(val);
      } else {
        ebf[e] = 0;
      }
    }
    return;
  }
  int cg = bid % 24, nb = bid / 24;
  int gid = nb * 256 + tid;
  if (gid >= BNTOT) return;
  int b = gid / NPOS, n = gid - b * NPOS;
  const float* xp = x + (size_t)b * 64 * NPOS + n;
  int ch0 = cg * 4;
  const float* wbase;
  float* obase;
  if (ch0 < 64)      { wbase = Wq + ch0 * 64;        obase = qws + ((size_t)b * 64 + ch0) * NPOS + n; }
  else if (ch0 < 80) { wbase = Wk + (ch0 - 64) * 64; obase = kws + ((size_t)b * 16 + (ch0 - 64)) * NPOS + n; }
  else               { wbase = Wv + (ch0 - 80) * 64; obase = vws + ((size_t)b * 16 + (ch0 - 80)) * NPOS + n; }

  float acc[4];
#pragma unroll
  for (int j = 0; j < 4; ++j) acc[j] = 0.f;
  for (int c = 0; c < 64; c += 4) {
    float x0 = xp[(c + 0) * NPOS], x1 = xp[(c + 1) * NPOS];
    float x2 = xp[(c + 2) * NPOS], x3 = xp[(c + 3) * NPOS];
#pragma unroll
    for (int j = 0; j < 4; ++j) {
      float4 w = *(const float4*)(wbase + j * 64 + c);
      acc[j] += w.x * x0 + w.y * x1 + w.z * x2 + w.w * x3;
    }
  }
#pragma unroll
  for (int j = 0; j < 4; ++j) obase[(size_t)j * NPOS] = acc[j];
}

// ---------------- P2: BN stats+finalize (blocks 0..79) | lambda_c partials (80..335) ----------------
// float4-vectorized loads on both paths (G13).
__global__ __launch_bounds__(256) void k_sl(const float* __restrict__ qws,
    const float* __restrict__ kws, const float* __restrict__ vws,
    const float* __restrict__ gq, const float* __restrict__ bq,
    const float* __restrict__ gv, const float* __restrict__ bv,
    float* __restrict__ st, float* __restrict__ lcacc) {
  int bid = blockIdx.x;
  int tid = threadIdx.x;
  int wid = tid >> 6;
  __shared__ float red[17][4];
  if (bid < 80) {
    int ch = bid;
    const float* p = (ch < 64) ? (qws + (size_t)ch * NPOS) : (vws + (size_t)(ch - 64) * NPOS);
    size_t pstride = (ch < 64) ? (size_t)64 * NPOS : (size_t)16 * NPOS;
    float s = 0.f, ss = 0.f;
    for (int b = 0; b < 4; ++b) {
      const float4* pp = (const float4*)(p + b * pstride);
      for (int i = tid; i < NPOS / 4; i += 256) {
        float4 g = pp[i];
        s += g.x + g.y + g.z + g.w;
        ss += g.x * g.x + g.y * g.y + g.z * g.z + g.w * g.w;
      }
    }
#pragma unroll
    for (int o = 32; o > 0; o >>= 1) { s += __shfl_xor(s, o, 64); ss += __shfl_xor(ss, o, 64); }
    if ((tid & 63) == 0) { red[0][wid] = s; red[1][wid] = ss; }
    __syncthreads();
    if (tid == 0) {
      float S = red[0][0] + red[0][1] + red[0][2] + red[0][3];
      float SS = red[1][0] + red[1][1] + red[1][2] + red[1][3];
      float mean = S / (float)BNTOT;
      float var = SS / (float)BNTOT - mean * mean;
      float inv = rsqrtf(var + 1e-5f);
      float g, be;
      if (ch < 64) { g = gq[ch]; be = bq[ch]; } else { g = gv[ch - 64]; be = bv[ch - 64]; }
      float sc = g * inv, sh = be - mean * sc;
      if (ch < 64) { st[ch] = sc; st[64 + ch] = sh; }
      else { st[128 + (ch - 64)] = sc; st[144 + (ch - 64)] = sh; }
    }
  } else {
    int bid2 = bid - 80;
    int b = bid2 >> 6, kc = (bid2 >> 2) & 15, seg = bid2 & 3;
    const float* kp = kws + ((size_t)b * 16 + kc) * NPOS;
    const float* vp = vws + (size_t)b * 16 * NPOS;
    float s = 0.f, acc[16];
#pragma unroll
    for (int v = 0; v < 16; ++v) acc[v] = 0.f;
    int m0 = seg * 688;                         // 688,688,688,680 (all mult of 4)
    int nf4 = (min(688, NPOS - m0)) >> 2;
    const float4* kp4 = (const float4*)(kp + m0);
    for (int i = tid; i < nf4; i += 256) {
      float4 kg = kp4[i];
      float e0 = __expf(kg.x), e1 = __expf(kg.y), e2 = __expf(kg.z), e3 = __expf(kg.w);
      s += e0 + e1 + e2 + e3;
#pragma unroll
      for (int v = 0; v < 16; ++v) {
        float4 vg = *(const float4*)(vp + (size_t)v * NPOS + m0 + i * 4);
        acc[v] += e0 * vg.x + e1 * vg.y + e2 * vg.z + e3 * vg.w;
      }
    }
#pragma unroll
    for (int o = 32; o > 0; o >>= 1) {
      s += __shfl_xor(s, o, 64);
#pragma unroll
      for (int v = 0; v < 16; ++v) acc[v] += __shfl_xor(acc[v], o, 64);
    }
    if ((tid & 63) == 0) { red[16][wid] = s; for (int v = 0; v < 16; ++v) red[v][wid] = acc[v]; }
    __syncthreads();
    if (tid < 17) {
      float tot = red[tid][0] + red[tid][1] + red[tid][2] + red[tid][3];
      atomicAdd(lcacc + ((size_t)b * 16 + kc) * 17 + tid, tot);
    }
  }
}

// ---------------- P3: vfrag (x-row tiling) + lc finalize ----------------
__global__ __launch_bounds__(256) void k_conv2(const float* __restrict__ vws,
    const float* __restrict__ st, const float* __restrict__ lcacc,
    uint4* __restrict__ vfrag, float* __restrict__ lc) {
  int idx = blockIdx.x * 256 + threadIdx.x;
  if (idx < NV2) {
    int rt = idx >> 7; int r = idx & 127;
    int ct = r >> 6, l = r & 63;
    int zm = rt / 14, ym = rt - zm * 14;
    int kh = l >> 5;
    int b = ct * 2 + ((l >> 4) & 1), v = l & 15;
    int mrow = zm * 196 + ym * 14;
    float sc = st[128 + v], sh = st[144 + v];
    unsigned int wds[4];
#pragma unroll
    for (int i = 0; i < 4; ++i) {
      int x0 = kh * 8 + 2 * i, x1 = x0 + 1;
      float f0 = 0.f, f1 = 0.f;
      if (x0 < 14) f0 = vws[((size_t)b * 16 + v) * NPOS + mrow + x0] * sc + sh;
      if (x1 < 14) f1 = vws[((size_t)b * 16 + v) * NPOS + mrow + x1] * sc + sh;
      wds[i] = (unsigned int)f2bf(f0) | ((unsigned int)f2bf(f1) << 16);
    }
    vfrag[(rt * 2 + ct) * 64 + l] = make_uint4(wds[0], wds[1], wds[2], wds[3]);
  } else if (idx < NV2 + N4T) {
    int t = idx - NV2;
    int b = t >> 8, kc = (t >> 4) & 15, v = t & 15;
    const float* la = lcacc + ((size_t)b * 16 + kc) * 17;
    float S = la[16];
    lc[((size_t)b * 16 + kc) * 16 + v] = st[128 + v] * (la[v] / S) + st[144 + v];
  }
}

// ---------------- P4: lambda_p — per-(k, 96-n group) LDS-windowed MFMA ----------------
// r20/r22 config + A-read software pipeline: iteration d+1's three A-fragment
// LDS reads are issued BEFORE iteration d's MFMAs (ds_read latency hides under
// the MFMA + B-load phase; only ~1.8 blocks/CU resident so TLP alone can't).
__global__ __launch_bounds__(256, 3) void k_lam(const unsigned short* __restrict__ ebf,
    const uint4* __restrict__ vfrag, unsigned int* __restrict__ lpb) {
  __shared__ unsigned int lds[12320];   // >= max(2*WDW3=10440, 12288)
  int tid = threadIdx.x;
  int w = tid >> 6, l = tid & 63;
  int orig = blockIdx.x;
  int bid = (orig & 7) * 58 + (orig >> 3);   // bijective: 464 = 8*58
  int k = bid / NGRP3, ng = bid - k * NGRP3;
  int n0 = ng * 96;
  int nmax = min(n0 + 95, NPOS - 1);
  int zx = nmax / 196, tx = nmax - zx * 196, yx = tx / 14, xx = tx - yx * 14;
  int b0 = (9841 - (zx * 729 + yx * 27 + xx)) & ~7;   // 16B-aligned window start

  const unsigned int* gsrc = (const unsigned int*)(ebf + (size_t)k * EROWS2 + b0);
#pragma unroll
  for (int it = 0; it < 6; ++it) {
    int ck = it * 256 + tid;
    if (ck < WDW3 / 4) {
      uint4 g = *(const uint4*)(gsrc + 4 * ck);
      unsigned int g4 = gsrc[4 * ck + 4];
      *(uint4*)(&lds[4 * ck]) = g;
      uint4 h;
      h.x = fsh(g.y, g.x, 16); h.y = fsh(g.z, g.y, 16);
      h.z = fsh(g.w, g.z, 16); h.w = fsh(g4, g.w, 16);
      *(uint4*)(&lds[WDW3 + 4 * ck]) = h;
    }
  }
  int i = l & 31, kh = l >> 5;
  int n_a = min(n0 + i, NPOS - 1);
  int n_b = min(n0 + 32 + i, NPOS - 1);
  int n_c = min(n0 + 64 + i, NPOS - 1);
  int za = n_a / 196, ta = n_a - za * 196, ya = ta / 14, xa = ta - ya * 14;
  int zb = n_b / 196, tb = n_b - zb * 196, yb = tb / 14, xb = tb - yb * 14;
  int zc = n_c / 196, tc = n_c - zc * 196, yc = tc / 14, xc = tc - yc * 14;
  int soff0 = 9841 - (za * 729 + ya * 27 + xa) - b0 + kh * 8;
  int soff1 = 9841 - (zb * 729 + yb * 27 + xb) - b0 + kh * 8;
  int soff2 = 9841 - (zc * 729 + yc * 27 + xc) - b0 + kh * 8;
  __syncthreads();

  f32x16 a0c0, a0c1, a1c0, a1c1, a2c0, a2c1;
#pragma unroll
  for (int q = 0; q < 16; ++q) {
    a0c0[q] = 0.f; a0c1[q] = 0.f; a1c0[q] = 0.f;
    a1c1[q] = 0.f; a2c0[q] = 0.f; a2c1[q] = 0.f;
  }

  int rtS = w * 49;
  int zm = rtS / 14, ym = rtS - zm * 14;
  int crel = zm * 729 + ym * 27;
  const uint4* vfp = vfrag + (size_t)(rtS * 2) * 64 + l;
  uint4 B0 = vfp[0], B1 = vfp[64];
  // prologue A loads for d=0
  uint4 A0, A1, A2;
  {
    int o0 = soff0 + crel, o1 = soff1 + crel, o2 = soff2 + crel;
    int ad0 = (o0 >> 1) + (o0 & 1) * WDW3;
    int ad1 = (o1 >> 1) + (o1 & 1) * WDW3;
    int ad2 = (o2 >> 1) + (o2 & 1) * WDW3;
    A0 = make_uint4(lds[ad0], lds[ad0 + 1], lds[ad0 + 2], lds[ad0 + 3]);
    A1 = make_uint4(lds[ad1], lds[ad1 + 1], lds[ad1 + 2], lds[ad1 + 3]);
    A2 = make_uint4(lds[ad2], lds[ad2 + 1], lds[ad2 + 2], lds[ad2 + 3]);
  }
  for (int d = 0; d < 49; ++d) {
    // next-iter state
    int creln = (d < 48) ? (crel + ((ym == 13) ? 378 : 27)) : crel;
    int ymn = (d < 48) ? ((ym == 13) ? 0 : ym + 1) : ym;
    const uint4* vfn = vfp + ((d < 48) ? 128 : 0);
    // issue next-iter B (global) and A (LDS) loads before this iter's MFMAs
    uint4 nB0 = vfn[0], nB1 = vfn[64];
    int o0 = soff0 + creln, o1 = soff1 + creln, o2 = soff2 + creln;
    int ad0 = (o0 >> 1) + (o0 & 1) * WDW3;
    int ad1 = (o1 >> 1) + (o1 & 1) * WDW3;
    int ad2 = (o2 >> 1) + (o2 & 1) * WDW3;
    uint4 nA0 = make_uint4(lds[ad0], lds[ad0 + 1], lds[ad0 + 2], lds[ad0 + 3]);
    uint4 nA1 = make_uint4(lds[ad1], lds[ad1 + 1], lds[ad1 + 2], lds[ad1 + 3]);
    uint4 nA2 = make_uint4(lds[ad2], lds[ad2 + 1], lds[ad2 + 2], lds[ad2 + 3]);
    __builtin_amdgcn_s_setprio(1);
    a0c0 = __builtin_amdgcn_mfma_f32_32x32x16_bf16(
        __builtin_bit_cast(bf16x8, A0), __builtin_bit_cast(bf16x8, B0), a0c0, 0, 0, 0);
    a0c1 = __builtin_amdgcn_mfma_f32_32x32x16_bf16(
        __builtin_bit_cast(bf16x8, A0), __builtin_bit_cast(bf16x8, B1), a0c1, 0, 0, 0);
    a1c0 = __builtin_amdgcn_mfma_f32_32x32x16_bf16(
        __builtin_bit_cast(bf16x8, A1), __builtin_bit_cast(bf16x8, B0), a1c0, 0, 0, 0);
    a1c1 = __builtin_amdgcn_mfma_f32_32x32x16_bf16(
        __builtin_bit_cast(bf16x8, A1), __builtin_bit_cast(bf16x8, B1), a1c1, 0, 0, 0);
    a2c0 = __builtin_amdgcn_mfma_f32_32x32x16_bf16(
        __builtin_bit_cast(bf16x8, A2), __builtin_bit_cast(bf16x8, B0), a2c0, 0, 0, 0);
    a2c1 = __builtin_amdgcn_mfma_f32_32x32x16_bf16(
        __builtin_bit_cast(bf16x8, A2), __builtin_bit_cast(bf16x8, B1), a2c1, 0, 0, 0);
    __builtin_amdgcn_s_setprio(0);
    A0 = nA0; A1 = nA1; A2 = nA2; B0 = nB0; B1 = nB1;
    vfp = vfn; ym = ymn; crel = creln;
  }

  // ---- tree reduction over m-quarter waves (reuse LDS; 6 sets x 1024 floats) ----
  __syncthreads();
  float* red = (float*)lds;
  if (w >= 2) {
    float* r0 = red + (w - 2) * 6144;
#pragma unroll
    for (int r = 0; r < 16; ++r) {
      r0[r * 64 + l] = a0c0[r];          r0[1024 + r * 64 + l] = a0c1[r];
      r0[2048 + r * 64 + l] = a1c0[r];   r0[3072 + r * 64 + l] = a1c1[r];
      r0[4096 + r * 64 + l] = a2c0[r];   r0[5120 + r * 64 + l] = a2c1[r];
    }
  }
  __syncthreads();
  if (w < 2) {
    const float* r0 = red + w * 6144;
#pragma unroll
    for (int r = 0; r < 16; ++r) {
      a0c0[r] += r0[r * 64 + l];         a0c1[r] += r0[1024 + r * 64 + l];
      a1c0[r] += r0[2048 + r * 64 + l];  a1c1[r] += r0[3072 + r * 64 + l];
      a2c0[r] += r0[4096 + r * 64 + l];  a2c1[r] += r0[5120 + r * 64 + l];
    }
  }
  __syncthreads();
  if (w == 1) {
#pragma unroll
    for (int r = 0; r < 16; ++r) {
      red[r * 64 + l] = a0c0[r];          red[1024 + r * 64 + l] = a0c1[r];
      red[2048 + r * 64 + l] = a1c0[r];   red[3072 + r * 64 + l] = a1c1[r];
      red[4096 + r * 64 + l] = a2c0[r];   red[5120 + r * 64 + l] = a2c1[r];
    }
  }
  __syncthreads();
  if (w == 0) {
#pragma unroll
    for (int r = 0; r < 16; ++r) {
      a0c0[r] += red[r * 64 + l];         a0c1[r] += red[1024 + r * 64 + l];
      a1c0[r] += red[2048 + r * 64 + l];  a1c1[r] += red[3072 + r * 64 + l];
      a2c0[r] += red[4096 + r * 64 + l];  a2c1[r] += red[5120 + r * 64 + l];
    }
    // dump finals to LDS as f32 fl[n_loc][b*16+v] (96 x 64)
    float* fl = (float*)lds;
    int bv0 = ((l >> 4) & 1) * 16 + (l & 15);   // bsel*16 + v
#define DUMP(ACC, NT, CT)                                                   \
    {                                                                       \
_Pragma("unroll")                                                           \
      for (int r = 0; r < 16; ++r) {                                        \
        int nl = (NT) * 32 + ((r & 3) + 8 * (r >> 2) + 4 * kh);             \
        fl[nl * 64 + (CT) * 32 + bv0] = ACC[r];                             \
      }                                                                     \
    }
    DUMP(a0c0, 0, 0) DUMP(a0c1, 0, 1)
    DUMP(a1c0, 1, 0) DUMP(a1c1, 1, 1)
    DUMP(a2c0, 2, 0) DUMP(a2c1, 2, 1)
#undef DUMP
  }
  __syncthreads();
  // cooperative packed store: 3072 dwords -> lp2[b][n][k][v] (32B segments)
  {
    const float* fl = (const float*)lds;
#pragma unroll
    for (int it = 0; it < 12; ++it) {
      int idx = it * 256 + tid;                 // 0..3071
      int vd = idx & 7, b = (idx >> 3) & 3, nl = idx >> 5;
      int n = n0 + nl;
      if (n < NPOS) {
        float2 f = *(const float2*)&fl[nl * 64 + b * 16 + 2 * vd];
        lpb[((size_t)(b * NPOS + n) * 16 + k) * 8 + vd] = pk2(f.x, f.y);
      }
    }
  }
}

// ---------------- P5: epilogue out = q_bn . (lambda_p + lambda_c), LDS-staged, 256 thr ----------------
// 344 blocks (4 b x 86 n-chunks of 32) x 256 thr. Thread = (h-pair, n_loc, vq).
__global__ __launch_bounds__(256) void k_ep(const unsigned int* __restrict__ lpb,
    const float* __restrict__ qws, const float* __restrict__ st,
    const float* __restrict__ lc, float* __restrict__ out) {
  __shared__ unsigned int laml[32 * 130];   // stride 130 dw: bank-spread
  __shared__ float qlds[64 * 33];           // stride 33: conflict-free
  __shared__ float lclds[256];
  int tid = threadIdx.x;
  int bid = blockIdx.x;
  int b = bid & 3, chk = bid >> 2;
  int n0 = chk * 32;
  // stage lambda_p slice: 32 n x 128 dw contiguous
  const uint4* lsrc = (const uint4*)(lpb + (size_t)(b * NPOS + n0) * 128);
#pragma unroll
  for (int it = 0; it < 4; ++it) {
    int idx4 = it * 256 + tid;              // 1024 uint4
    uint4 g = lsrc[idx4];
    int n_loc = idx4 >> 5, rem = (idx4 & 31) * 4;
    unsigned int* d = &laml[n_loc * 130 + rem];
    d[0] = g.x; d[1] = g.y; d[2] = g.z; d[3] = g.w;
  }
  // stage q (64 ch x 32 n), BN applied at stage time
  const float* qb = qws + (size_t)b * 64 * NPOS + n0;
#pragma unroll
  for (int it = 0; it < 2; ++it) {
    int idx4 = it * 256 + tid;              // 512 float4
    int ch = idx4 >> 3, c4 = (idx4 & 7) * 4;
    float4 g = *(const float4*)(qb + (size_t)ch * NPOS + c4);
    float sc = st[ch], sh = st[64 + ch];
    float* d = &qlds[ch * 33 + c4];
    d[0] = g.x * sc + sh; d[1] = g.y * sc + sh;
    d[2] = g.z * sc + sh; d[3] = g.w * sc + sh;
  }
  // stage lc for this b
  lclds[tid] = lc[b * 256 + tid];
  __syncthreads();
  int hh = tid >> 7;                        // h-pair: h in {2hh, 2hh+1}
  int rem2 = tid & 127;
  int vq = rem2 & 3, n_loc = rem2 >> 2;
  int n = n0 + n_loc;
  if (n >= NPOS) return;
  float y[8];
#pragma unroll
  for (int i = 0; i < 8; ++i) y[i] = 0.f;
#pragma unroll
  for (int k = 0; k < 16; ++k) {
    uint2 lp = *(const uint2*)&laml[n_loc * 130 + k * 8 + vq * 2];
    const float* lcr = &lclds[k * 16 + vq * 4];
    float l0 = ubf(lp.x, 0) + lcr[0];
    float l1 = ubf(lp.x, 16) + lcr[1];
    float l2 = ubf(lp.y, 0) + lcr[2];
    float l3 = ubf(lp.y, 16) + lcr[3];
#pragma unroll
    for (int hx = 0; hx < 2; ++hx) {
      float q = qlds[((hh * 2 + hx) * 16 + k) * 33 + n_loc];
      y[hx * 4 + 0] += q * l0; y[hx * 4 + 1] += q * l1;
      y[hx * 4 + 2] += q * l2; y[hx * 4 + 3] += q * l3;
    }
  }
#pragma unroll
  for (int hx = 0; hx < 2; ++hx) {
    size_t ob = ((size_t)b * 64 + (hh * 2 + hx) * 16 + vq * 4) * NPOS + n;
#pragma unroll
    for (int j = 0; j < 4; ++j)
      out[ob + (size_t)j * NPOS] = y[hx * 4 + j];
  }
}

extern "C" void kernel_launch(void* const* d_in, const int* in_sizes, int n_in,
                              void* d_out, int out_size, void* d_ws, size_t ws_size,
                              hipStream_t stream) {
  const float* x   = (const float*)d_in[0];
  const float* Wq  = (const float*)d_in[1];
  const float* Wk  = (const float*)d_in[2];
  const float* Wv  = (const float*)d_in[3];
  const float* rpe = (const float*)d_in[4];
  const float* gq  = (const float*)d_in[5];
  const float* bq  = (const float*)d_in[6];
  const float* gv  = (const float*)d_in[7];
  const float* bv  = (const float*)d_in[8];
  float* out = (float*)d_out;
  char* ws = (char*)d_ws;
  float* qws = (float*)(ws + WS_Q);
  float* kws = (float*)(ws + WS_K);
  float* vws = (float*)(ws + WS_V);
  float* st  = (float*)(ws + WS_ST);
  float* la  = (float*)(ws + WS_LA);
  float* lcp = (float*)(ws + WS_LC);
  unsigned short* ebf = (unsigned short*)(ws + WS_E2);
  unsigned int* lpb = (unsigned int*)(ws + WS_LP);
  uint4* vfrag = (uint4*)(ws + WS_VF);

  k_qkv<<<1340, 256, 0, stream>>>(x, Wq, Wk, Wv, rpe, qws, kws, vws, ebf, la);
  k_sl<<<336, 256, 0, stream>>>(qws, kws, vws, gq, bq, gv, bv, st, la);
  k_conv2<<<102, 256, 0, stream>>>(vws, st, la, vfrag, lcp);
  k_lam<<<16 * NGRP3, 256, 0, stream>>>(ebf, vfrag, lpb);
  k_ep<<<344, 256, 0, stream>>>(lpb, qws, st, lcp, out);
}

// Round 24
// 49.744 us; speedup vs baseline: 1.0183x; 1.0183x over previous
//
#include <hip/hip_runtime.h>
#include <hip/hip_bf16.h>

#define NPOS 2744      // 14^3
#define BB 4
#define BNTOT (BB*NPOS)   // 10976
#define RELVOL 19683   // 27^3
#define EROWS2 19688       // padded elems per k-row (mult of 4)
#define NRT 196            // (zm,ym) m-row-tiles
#define NV2 (NRT*2*64)     // vfrag entries
#define N4T 1024           // lc
#define NGRP3 29           // 96-n groups
#define WDW3 5220          // dwords per LDS window copy (10440 elems)

typedef __bf16 bf16x8 __attribute__((ext_vector_type(8)));
typedef float f32x16 __attribute__((ext_vector_type(16)));

// ---- workspace layout (bytes) ----
#define WS_Q  0u           // f32 [4][64][2744]
#define WS_K  2809856u     // f32 [4][16][2744]  (dead after k_sl; vfrag aliases it)
#define WS_V  3512320u     // f32 [4][16][2744]
#define WS_ST 4214784u     // f32 [160] scale/shift
#define WS_LA 4216192u     // f32 [1088] lc accum
#define WS_LC 4220544u     // f32 [4][16][16]
#define WS_E2 4224640u     // u16 [16][EROWS2] bf16 E table, k-MAJOR (630KB) + 2KB pad
#define WS_LP 4856704u     // u16 [4 b][2744 n][16 k][16 v] bf16 lambda_p (5.6MB)
#define WS_VF WS_K         // uint4 [196][2][64] v B-fragments

__device__ inline unsigned short f2bf(float f) {
  unsigned int u = __float_as_uint(f);
  return (unsigned short)((u + 0x7fffu + ((u >> 16) & 1u)) >> 16);
}
__device__ inline unsigned int fsh(unsigned int hi, unsigned int lo, int shbits) {
  return (unsigned int)(((((unsigned long long)hi) << 32) | lo) >> shbits);
}
__device__ inline unsigned int pk2(float a, float b) {
  return (unsigned int)f2bf(a) | ((unsigned int)f2bf(b) << 16);
}
__device__ inline float ubf(unsigned int d, int hf) {
  return __uint_as_float(((d >> hf) & 0xFFFFu) << 16);
}

// ---------------- P1: qkv projections (blocks 0..1031, 4-ch groups) + E-table build (1032..1339) ----------------
__global__ __launch_bounds__(256) void k_qkv(const float* __restrict__ x,
    const float* __restrict__ Wq, const float* __restrict__ Wk, const float* __restrict__ Wv,
    const float* __restrict__ rpe,
    float* __restrict__ qws, float* __restrict__ kws, float* __restrict__ vws,
    unsigned short* __restrict__ ebf, float* __restrict__ la) {
  int bid = blockIdx.x;
  int tid = threadIdx.x;
  if (bid >= 1032) {
    int bid2 = bid - 1032;                     // 0..307
    if (bid2 == 0 && tid < 272) ((float4*)la)[tid] = make_float4(0.f, 0.f, 0.f, 0.f);
    const int TOT = 16 * EROWS2 + 1024;        // +1024 elems: zero pad after table
    for (int e = bid2 * 256 + tid; e < TOT; e += 308 * 256) {
      if (e < 16 * EROWS2) {
        int k = e / EROWS2;
        int i = e - k * EROWS2;
        float val = (i < RELVOL) ? rpe[i * 16 + k] : 0.f;
        ebf[e] = f2bf(val);
      } else {
        ebf[e] = 0;
      }
    }
    return;
  }
  int cg = bid % 24, nb = bid / 24;
  int gid = nb * 256 + tid;
  if (gid >= BNTOT) return;
  int b = gid / NPOS, n = gid - b * NPOS;
  const float* xp = x + (size_t)b * 64 * NPOS + n;
  int ch0 = cg * 4;
  const float* wbase;
  float* obase;
  if (ch0 < 64)      { wbase = Wq + ch0 * 64;        obase = qws + ((size_t)b * 64 + ch0) * NPOS + n; }
  else if (ch0 < 80) { wbase = Wk + (ch0 - 64) * 64; obase = kws + ((size_t)b * 16 + (ch0 - 64)) * NPOS + n; }
  else               { wbase = Wv + (ch0 - 80) * 64; obase = vws + ((size_t)b * 16 + (ch0 - 80)) * NPOS + n; }

  float acc[4];
#pragma unroll
  for (int j = 0; j < 4; ++j) acc[j] = 0.f;
  for (int c = 0; c < 64; c += 4) {
    float x0 = xp[(c + 0) * NPOS], x1 = xp[(c + 1) * NPOS];
    float x2 = xp[(c + 2) * NPOS], x3 = xp[(c + 3) * NPOS];
#pragma unroll
    for (int j = 0; j < 4; ++j) {
      float4 w = *(const float4*)(wbase + j * 64 + c);
      acc[j] += w.x * x0 + w.y * x1 + w.z * x2 + w.w * x3;
    }
  }
#pragma unroll
  for (int j = 0; j < 4; ++j) obase[(size_t)j * NPOS] = acc[j];
}

// ---------------- P2: BN stats+finalize (blocks 0..79) | lambda_c partials (80..335) ----------------
// float4-vectorized loads on both paths (G13).
__global__ __launch_bounds__(256) void k_sl(const float* __restrict__ qws,
    const float* __restrict__ kws, const float* __restrict__ vws,
    const float* __restrict__ gq, const float* __restrict__ bq,
    const float* __restrict__ gv, const float* __restrict__ bv,
    float* __restrict__ st, float* __restrict__ lcacc) {
  int bid = blockIdx.x;
  int tid = threadIdx.x;
  int wid = tid >> 6;
  __shared__ float red[17][4];
  if (bid < 80) {
    int ch = bid;
    const float* p = (ch < 64) ? (qws + (size_t)ch * NPOS) : (vws + (size_t)(ch - 64) * NPOS);
    size_t pstride = (ch < 64) ? (size_t)64 * NPOS : (size_t)16 * NPOS;
    float s = 0.f, ss = 0.f;
    for (int b = 0; b < 4; ++b) {
      const float4* pp = (const float4*)(p + b * pstride);
      for (int i = tid; i < NPOS / 4; i += 256) {
        float4 g = pp[i];
        s += g.x + g.y + g.z + g.w;
        ss += g.x * g.x + g.y * g.y + g.z * g.z + g.w * g.w;
      }
    }
#pragma unroll
    for (int o = 32; o > 0; o >>= 1) { s += __shfl_xor(s, o, 64); ss += __shfl_xor(ss, o, 64); }
    if ((tid & 63) == 0) { red[0][wid] = s; red[1][wid] = ss; }
    __syncthreads();
    if (tid == 0) {
      float S = red[0][0] + red[0][1] + red[0][2] + red[0][3];
      float SS = red[1][0] + red[1][1] + red[1][2] + red[1][3];
      float mean = S / (float)BNTOT;
      float var = SS / (float)BNTOT - mean * mean;
      float inv = rsqrtf(var + 1e-5f);
      float g, be;
      if (ch < 64) { g = gq[ch]; be = bq[ch]; } else { g = gv[ch - 64]; be = bv[ch - 64]; }
      float sc = g * inv, sh = be - mean * sc;
      if (ch < 64) { st[ch] = sc; st[64 + ch] = sh; }
      else { st[128 + (ch - 64)] = sc; st[144 + (ch - 64)] = sh; }
    }
  } else {
    int bid2 = bid - 80;
    int b = bid2 >> 6, kc = (bid2 >> 2) & 15, seg = bid2 & 3;
    const float* kp = kws + ((size_t)b * 16 + kc) * NPOS;
    const float* vp = vws + (size_t)b * 16 * NPOS;
    float s = 0.f, acc[16];
#pragma unroll
    for (int v = 0; v < 16; ++v) acc[v] = 0.f;
    int m0 = seg * 688;                         // 688,688,688,680 (all mult of 4)
    int nf4 = (min(688, NPOS - m0)) >> 2;
    const float4* kp4 = (const float4*)(kp + m0);
    for (int i = tid; i < nf4; i += 256) {
      float4 kg = kp4[i];
      float e0 = __expf(kg.x), e1 = __expf(kg.y), e2 = __expf(kg.z), e3 = __expf(kg.w);
      s += e0 + e1 + e2 + e3;
#pragma unroll
      for (int v = 0; v < 16; ++v) {
        float4 vg = *(const float4*)(vp + (size_t)v * NPOS + m0 + i * 4);
        acc[v] += e0 * vg.x + e1 * vg.y + e2 * vg.z + e3 * vg.w;
      }
    }
#pragma unroll
    for (int o = 32; o > 0; o >>= 1) {
      s += __shfl_xor(s, o, 64);
#pragma unroll
      for (int v = 0; v < 16; ++v) acc[v] += __shfl_xor(acc[v], o, 64);
    }
    if ((tid & 63) == 0) { red[16][wid] = s; for (int v = 0; v < 16; ++v) red[v][wid] = acc[v]; }
    __syncthreads();
    if (tid < 17) {
      float tot = red[tid][0] + red[tid][1] + red[tid][2] + red[tid][3];
      atomicAdd(lcacc + ((size_t)b * 16 + kc) * 17 + tid, tot);
    }
  }
}

// ---------------- P3: vfrag (x-row tiling) + lc finalize ----------------
__global__ __launch_bounds__(256) void k_conv2(const float* __restrict__ vws,
    const float* __restrict__ st, const float* __restrict__ lcacc,
    uint4* __restrict__ vfrag, float* __restrict__ lc) {
  int idx = blockIdx.x * 256 + threadIdx.x;
  if (idx < NV2) {
    int rt = idx >> 7; int r = idx & 127;
    int ct = r >> 6, l = r & 63;
    int zm = rt / 14, ym = rt - zm * 14;
    int kh = l >> 5;
    int b = ct * 2 + ((l >> 4) & 1), v = l & 15;
    int mrow = zm * 196 + ym * 14;
    float sc = st[128 + v], sh = st[144 + v];
    unsigned int wds[4];
#pragma unroll
    for (int i = 0; i < 4; ++i) {
      int x0 = kh * 8 + 2 * i, x1 = x0 + 1;
      float f0 = 0.f, f1 = 0.f;
      if (x0 < 14) f0 = vws[((size_t)b * 16 + v) * NPOS + mrow + x0] * sc + sh;
      if (x1 < 14) f1 = vws[((size_t)b * 16 + v) * NPOS + mrow + x1] * sc + sh;
      wds[i] = (unsigned int)f2bf(f0) | ((unsigned int)f2bf(f1) << 16);
    }
    vfrag[(rt * 2 + ct) * 64 + l] = make_uint4(wds[0], wds[1], wds[2], wds[3]);
  } else if (idx < NV2 + N4T) {
    int t = idx - NV2;
    int b = t >> 8, kc = (t >> 4) & 15, v = t & 15;
    const float* la = lcacc + ((size_t)b * 16 + kc) * 17;
    float S = la[16];
    lc[((size_t)b * 16 + kc) * 16 + v] = st[128 + v] * (la[v] / S) + st[144 + v];
  }
}

// ---------------- P4: lambda_p — per-(k, 96-n group) LDS-windowed MFMA ----------------
// Best configuration (r22, 50.0us): XCD-swizzled (464 = 8*58), 3 n-tiles/wave
// sharing 2 B frags, cooperative coalesced bf16 tail.
__global__ __launch_bounds__(256, 3) void k_lam(const unsigned short* __restrict__ ebf,
    const uint4* __restrict__ vfrag, unsigned int* __restrict__ lpb) {
  __shared__ unsigned int lds[12320];   // >= max(2*WDW3=10440, 12288)
  int tid = threadIdx.x;
  int w = tid >> 6, l = tid & 63;
  int orig = blockIdx.x;
  int bid = (orig & 7) * 58 + (orig >> 3);   // bijective: 464 = 8*58
  int k = bid / NGRP3, ng = bid - k * NGRP3;
  int n0 = ng * 96;
  int nmax = min(n0 + 95, NPOS - 1);
  int zx = nmax / 196, tx = nmax - zx * 196, yx = tx / 14, xx = tx - yx * 14;
  int b0 = (9841 - (zx * 729 + yx * 27 + xx)) & ~7;   // 16B-aligned window start

  const unsigned int* gsrc = (const unsigned int*)(ebf + (size_t)k * EROWS2 + b0);
#pragma unroll
  for (int it = 0; it < 6; ++it) {
    int ck = it * 256 + tid;
    if (ck < WDW3 / 4) {
      uint4 g = *(const uint4*)(gsrc + 4 * ck);
      unsigned int g4 = gsrc[4 * ck + 4];
      *(uint4*)(&lds[4 * ck]) = g;
      uint4 h;
      h.x = fsh(g.y, g.x, 16); h.y = fsh(g.z, g.y, 16);
      h.z = fsh(g.w, g.z, 16); h.w = fsh(g4, g.w, 16);
      *(uint4*)(&lds[WDW3 + 4 * ck]) = h;
    }
  }
  int i = l & 31, kh = l >> 5;
  int n_a = min(n0 + i, NPOS - 1);
  int n_b = min(n0 + 32 + i, NPOS - 1);
  int n_c = min(n0 + 64 + i, NPOS - 1);
  int za = n_a / 196, ta = n_a - za * 196, ya = ta / 14, xa = ta - ya * 14;
  int zb = n_b / 196, tb = n_b - zb * 196, yb = tb / 14, xb = tb - yb * 14;
  int zc = n_c / 196, tc = n_c - zc * 196, yc = tc / 14, xc = tc - yc * 14;
  int soff0 = 9841 - (za * 729 + ya * 27 + xa) - b0 + kh * 8;
  int soff1 = 9841 - (zb * 729 + yb * 27 + xb) - b0 + kh * 8;
  int soff2 = 9841 - (zc * 729 + yc * 27 + xc) - b0 + kh * 8;
  __syncthreads();

  f32x16 a0c0, a0c1, a1c0, a1c1, a2c0, a2c1;
#pragma unroll
  for (int q = 0; q < 16; ++q) {
    a0c0[q] = 0.f; a0c1[q] = 0.f; a1c0[q] = 0.f;
    a1c1[q] = 0.f; a2c0[q] = 0.f; a2c1[q] = 0.f;
  }

  int rtS = w * 49;
  int zm = rtS / 14, ym = rtS - zm * 14;
  int crel = zm * 729 + ym * 27;
  const uint4* vfp = vfrag + (size_t)(rtS * 2) * 64 + l;
  uint4 B0 = vfp[0], B1 = vfp[64];
  for (int d = 0; d < 49; ++d) {
    const uint4* vfn = vfp + ((d < 48) ? 128 : 0);
    uint4 nB0 = vfn[0], nB1 = vfn[64];
    int o0 = soff0 + crel, o1 = soff1 + crel, o2 = soff2 + crel;
    int ad0 = (o0 >> 1) + (o0 & 1) * WDW3;
    int ad1 = (o1 >> 1) + (o1 & 1) * WDW3;
    int ad2 = (o2 >> 1) + (o2 & 1) * WDW3;
    uint4 A0 = make_uint4(lds[ad0], lds[ad0 + 1], lds[ad0 + 2], lds[ad0 + 3]);
    uint4 A1 = make_uint4(lds[ad1], lds[ad1 + 1], lds[ad1 + 2], lds[ad1 + 3]);
    uint4 A2 = make_uint4(lds[ad2], lds[ad2 + 1], lds[ad2 + 2], lds[ad2 + 3]);
    __builtin_amdgcn_s_setprio(1);
    a0c0 = __builtin_amdgcn_mfma_f32_32x32x16_bf16(
        __builtin_bit_cast(bf16x8, A0), __builtin_bit_cast(bf16x8, B0), a0c0, 0, 0, 0);
    a0c1 = __builtin_amdgcn_mfma_f32_32x32x16_bf16(
        __builtin_bit_cast(bf16x8, A0), __builtin_bit_cast(bf16x8, B1), a0c1, 0, 0, 0);
    a1c0 = __builtin_amdgcn_mfma_f32_32x32x16_bf16(
        __builtin_bit_cast(bf16x8, A1), __builtin_bit_cast(bf16x8, B0), a1c0, 0, 0, 0);
    a1c1 = __builtin_amdgcn_mfma_f32_32x32x16_bf16(
        __builtin_bit_cast(bf16x8, A1), __builtin_bit_cast(bf16x8, B1), a1c1, 0, 0, 0);
    a2c0 = __builtin_amdgcn_mfma_f32_32x32x16_bf16(
        __builtin_bit_cast(bf16x8, A2), __builtin_bit_cast(bf16x8, B0), a2c0, 0, 0, 0);
    a2c1 = __builtin_amdgcn_mfma_f32_32x32x16_bf16(
        __builtin_bit_cast(bf16x8, A2), __builtin_bit_cast(bf16x8, B1), a2c1, 0, 0, 0);
    __builtin_amdgcn_s_setprio(0);
    B0 = nB0; B1 = nB1; vfp = vfn;
    ++ym;
    if (ym == 14) { ym = 0; crel += 378; } else { crel += 27; }
  }

  // ---- tree reduction over m-quarter waves (reuse LDS; 6 sets x 1024 floats) ----
  __syncthreads();
  float* red = (float*)lds;
  if (w >= 2) {
    float* r0 = red + (w - 2) * 6144;
#pragma unroll
    for (int r = 0; r < 16; ++r) {
      r0[r * 64 + l] = a0c0[r];          r0[1024 + r * 64 + l] = a0c1[r];
      r0[2048 + r * 64 + l] = a1c0[r];   r0[3072 + r * 64 + l] = a1c1[r];
      r0[4096 + r * 64 + l] = a2c0[r];   r0[5120 + r * 64 + l] = a2c1[r];
    }
  }
  __syncthreads();
  if (w < 2) {
    const float* r0 = red + w * 6144;
#pragma unroll
    for (int r = 0; r < 16; ++r) {
      a0c0[r] += r0[r * 64 + l];         a0c1[r] += r0[1024 + r * 64 + l];
      a1c0[r] += r0[2048 + r * 64 + l];  a1c1[r] += r0[3072 + r * 64 + l];
      a2c0[r] += r0[4096 + r * 64 + l];  a2c1[r] += r0[5120 + r * 64 + l];
    }
  }
  __syncthreads();
  if (w == 1) {
#pragma unroll
    for (int r = 0; r < 16; ++r) {
      red[r * 64 + l] = a0c0[r];          red[1024 + r * 64 + l] = a0c1[r];
      red[2048 + r * 64 + l] = a1c0[r];   red[3072 + r * 64 + l] = a1c1[r];
      red[4096 + r * 64 + l] = a2c0[r];   red[5120 + r * 64 + l] = a2c1[r];
    }
  }
  __syncthreads();
  if (w == 0) {
#pragma unroll
    for (int r = 0; r < 16; ++r) {
      a0c0[r] += red[r * 64 + l];         a0c1[r] += red[1024 + r * 64 + l];
      a1c0[r] += red[2048 + r * 64 + l];  a1c1[r] += red[3072 + r * 64 + l];
      a2c0[r] += red[4096 + r * 64 + l];  a2c1[r] += red[5120 + r * 64 + l];
    }
    // dump finals to LDS as f32 fl[n_loc][b*16+v] (96 x 64)
    float* fl = (float*)lds;
    int bv0 = ((l >> 4) & 1) * 16 + (l & 15);   // bsel*16 + v
#define DUMP(ACC, NT, CT)                                                   \
    {                                                                       \
_Pragma("unroll")                                                           \
      for (int r = 0; r < 16; ++r) {                                        \
        int nl = (NT) * 32 + ((r & 3) + 8 * (r >> 2) + 4 * kh);             \
        fl[nl * 64 + (CT) * 32 + bv0] = ACC[r];                             \
      }                                                                     \
    }
    DUMP(a0c0, 0, 0) DUMP(a0c1, 0, 1)
    DUMP(a1c0, 1, 0) DUMP(a1c1, 1, 1)
    DUMP(a2c0, 2, 0) DUMP(a2c1, 2, 1)
#undef DUMP
  }
  __syncthreads();
  // cooperative packed store: 3072 dwords -> lp2[b][n][k][v] (32B segments)
  {
    const float* fl = (const float*)lds;
#pragma unroll
    for (int it = 0; it < 12; ++it) {
      int idx = it * 256 + tid;                 // 0..3071
      int vd = idx & 7, b = (idx >> 3) & 3, nl = idx >> 5;
      int n = n0 + nl;
      if (n < NPOS) {
        float2 f = *(const float2*)&fl[nl * 64 + b * 16 + 2 * vd];
        lpb[((size_t)(b * NPOS + n) * 16 + k) * 8 + vd] = pk2(f.x, f.y);
      }
    }
  }
}

// ---------------- P5: epilogue out = q_bn . (lambda_p + lambda_c), LDS-staged ----------------
__global__ __launch_bounds__(128) void k_ep(const unsigned int* __restrict__ lpb,
    const float* __restrict__ qws, const float* __restrict__ st,
    const float* __restrict__ lc, float* __restrict__ out) {
  __shared__ unsigned int laml[32 * 130];   // stride 130 dw: bank-spread
  __shared__ float qlds[64 * 33];           // stride 33: conflict-free
  __shared__ float lclds[256];
  int tid = threadIdx.x;
  int bid = blockIdx.x;
  int b = bid & 3, chk = bid >> 2;
  int n0 = chk * 32;
  // stage lambda_p slice: 32 n x 128 dw contiguous
  const uint4* lsrc = (const uint4*)(lpb + (size_t)(b * NPOS + n0) * 128);
#pragma unroll
  for (int it = 0; it < 8; ++it) {
    int idx4 = it * 128 + tid;              // 1024 uint4
    uint4 g = lsrc[idx4];
    int n_loc = idx4 >> 5, rem = (idx4 & 31) * 4;
    unsigned int* d = &laml[n_loc * 130 + rem];
    d[0] = g.x; d[1] = g.y; d[2] = g.z; d[3] = g.w;
  }
  // stage q (64 ch x 32 n), BN applied at stage time
  const float* qb = qws + (size_t)b * 64 * NPOS + n0;
#pragma unroll
  for (int it = 0; it < 4; ++it) {
    int idx4 = it * 128 + tid;              // 512 float4
    int ch = idx4 >> 3, c4 = (idx4 & 7) * 4;
    float4 g = *(const float4*)(qb + (size_t)ch * NPOS + c4);
    float sc = st[ch], sh = st[64 + ch];
    float* d = &qlds[ch * 33 + c4];
    d[0] = g.x * sc + sh; d[1] = g.y * sc + sh;
    d[2] = g.z * sc + sh; d[3] = g.w * sc + sh;
  }
  // stage lc for this b
  lclds[tid] = lc[b * 256 + tid];
  lclds[128 + tid] = lc[b * 256 + 128 + tid];
  __syncthreads();
  int vq = tid & 3, n_loc = tid >> 2;
  int n = n0 + n_loc;
  if (n >= NPOS) return;
  float y[16];
#pragma unroll
  for (int i = 0; i < 16; ++i) y[i] = 0.f;
#pragma unroll
  for (int k = 0; k < 16; ++k) {
    uint2 lp = *(const uint2*)&laml[n_loc * 130 + k * 8 + vq * 2];
    const float* lcr = &lclds[k * 16 + vq * 4];
    float l0 = ubf(lp.x, 0) + lcr[0];
    float l1 = ubf(lp.x, 16) + lcr[1];
    float l2 = ubf(lp.y, 0) + lcr[2];
    float l3 = ubf(lp.y, 16) + lcr[3];
#pragma unroll
    for (int h = 0; h < 4; ++h) {
      float q = qlds[(h * 16 + k) * 33 + n_loc];
      y[h * 4 + 0] += q * l0; y[h * 4 + 1] += q * l1;
      y[h * 4 + 2] += q * l2; y[h * 4 + 3] += q * l3;
    }
  }
  size_t ob = ((size_t)b * 64 + vq * 4) * NPOS + n;
#pragma unroll
  for (int h = 0; h < 4; ++h)
#pragma unroll
    for (int j = 0; j < 4; ++j)
      out[ob + (size_t)(h * 16 + j) * NPOS] = y[h * 4 + j];
}

extern "C" void kernel_launch(void* const* d_in, const int* in_sizes, int n_in,
                              void* d_out, int out_size, void* d_ws, size_t ws_size,
                              hipStream_t stream) {
  const float* x   = (const float*)d_in[0];
  const float* Wq  = (const float*)d_in[1];
  const float* Wk  = (const float*)d_in[2];
  const float* Wv  = (const float*)d_in[3];
  const float* rpe = (const float*)d_in[4];
  const float* gq  = (const float*)d_in[5];
  const float* bq  = (const float*)d_in[6];
  const float* gv  = (const float*)d_in[7];
  const float* bv  = (const float*)d_in[8];
  float* out = (float*)d_out;
  char* ws = (char*)d_ws;
  float* qws = (float*)(ws + WS_Q);
  float* kws = (float*)(ws + WS_K);
  float* vws = (float*)(ws + WS_V);
  float* st  = (float*)(ws + WS_ST);
  float* la  = (float*)(ws + WS_LA);
  float* lcp = (float*)(ws + WS_LC);
  unsigned short* ebf = (unsigned short*)(ws + WS_E2);
  unsigned int* lpb = (unsigned int*)(ws + WS_LP);
  uint4* vfrag = (uint4*)(ws + WS_VF);

  k_qkv<<<1340, 256, 0, stream>>>(x, Wq, Wk, Wv, rpe, qws, kws, vws, ebf, la);
  k_sl<<<336, 256, 0, stream>>>(qws, kws, vws, gq, bq, gv, bv, st, la);
  k_conv2<<<102, 256, 0, stream>>>(vws, st, la, vfrag, lcp);
  k_lam<<<16 * NGRP3, 256, 0, stream>>>(ebf, vfrag, lpb);
  k_ep<<<344, 128, 0, stream>>>(lpb, qws, st, lcp, out);
}